// Round 2
// baseline (423.259 us; speedup 1.0000x reference)
//
#include <hip/hip_runtime.h>

#define S1 512
#define NIMG 64

typedef float f4v __attribute__((ext_vector_type(4)));
typedef float f2v __attribute__((ext_vector_type(2)));

__device__ __forceinline__ int refl(int a, int L) {
    a = (a < 0) ? (-a - 1) : a;
    a = (a >= L) ? (2 * L - 1 - a) : a;
    return a;
}

// Non-temporal stores for write-only wavelet bands (never re-read; keep
// ll1/ll2 resident in L2/L3 for the next level's fetch instead).
__device__ __forceinline__ void st_nt_f4(float* p, float a, float b, float c, float d) {
    f4v w = {a, b, c, d};
    __builtin_nontemporal_store(w, (f4v*)p);
}
__device__ __forceinline__ void st_nt_f2(float* p, float a, float b) {
    f2v w = {a, b};
    __builtin_nontemporal_store(w, (f2v*)p);
}

// ---------------------------------------------------------------------------
// Level 1: undecimated 5/7-tap filters, fused W-pass + H-pass + q2c.
// 64x64 output tile per block, two 32-row halves.
// CHANGE vs prev: no LDS input staging. The W-filter (stage A) reads its
// 12-float window directly from global; the 3x horizontal overlap between
// neighboring threads is absorbed by L1 (contiguous 256B segments per
// quarter-wave). LDS drops 31.6 -> 20.7 KB, barriers 6 -> 4 per block,
// __launch_bounds__(256,5) caps VGPR at 102 so occupancy hits 5 blocks/CU.
// ---------------------------------------------------------------------------
__global__ __launch_bounds__(256, 5) void k_level1(
    const float* __restrict__ x,
    const float* __restrict__ h0o_g, const float* __restrict__ h1o_g,
    float* __restrict__ ll1, float* __restrict__ yh0)
{
    __shared__ float lo_s[38 * 68];   // 10.33 KB
    __shared__ float hi_s[38 * 68];   // 10.33 KB

    const int t  = threadIdx.x;
    const int c0 = blockIdx.x * 64;
    const int r0 = blockIdx.y * 64;
    const int n  = blockIdx.z;
    const float* __restrict__ xn  = x   + (size_t)n * (S1 * S1);
    float* __restrict__ lln       = ll1 + (size_t)n * (S1 * S1);
    float* __restrict__ yhn       = yh0 + (size_t)n * (6 * 256 * 256 * 2);

    float f0[5], f1[7];
#pragma unroll
    for (int i = 0; i < 5; ++i) f0[i] = h0o_g[i];
#pragma unroll
    for (int i = 0; i < 7; ++i) f1[i] = h1o_g[i];

    const float SQH = 0.70710678118654752440f;
    const bool safe = (c0 >= 4) && (c0 + 67 < S1);   // interior in col direction

    for (int h = 0; h < 2; ++h) {
        const int gr0 = r0 + 32 * h - 3;

        // ---- stage A: row filter straight from global, 4 outputs per item ----
        // window: global cols c0-4+4cg .. +11 ; lo[c] taps V[c+2..c+6],
        // hi[c] taps V[c+1..c+7] (V index = col - (c0-4+4cg)).
        for (int l = t; l < 38 * 16; l += 256) {
            int rl = l >> 4, cg = l & 15;
            int ar = refl(gr0 + rl, S1);
            const float* __restrict__ row = &xn[(size_t)ar * S1];
            const int gc0 = c0 - 4 + 4 * cg;
            float V[12];
            if (safe || (gc0 >= 0 && gc0 + 11 < S1)) {
#pragma unroll
                for (int j = 0; j < 3; ++j) {
                    float4 v = *(const float4*)&row[gc0 + 4 * j];
                    V[4*j+0] = v.x; V[4*j+1] = v.y; V[4*j+2] = v.z; V[4*j+3] = v.w;
                }
            } else {
#pragma unroll
                for (int k = 0; k < 12; ++k)
                    V[k] = row[refl(gc0 + k, S1)];
            }
            float lov[4], hiv[4];
#pragma unroll
            for (int cc = 0; cc < 4; ++cc) {
                lov[cc] = f0[0]*V[cc+6] + f0[1]*V[cc+5] + f0[2]*V[cc+4]
                        + f0[3]*V[cc+3] + f0[4]*V[cc+2];
                hiv[cc] = f1[0]*V[cc+7] + f1[1]*V[cc+6] + f1[2]*V[cc+5]
                        + f1[3]*V[cc+4] + f1[4]*V[cc+3] + f1[5]*V[cc+2]
                        + f1[6]*V[cc+1];
            }
            *(float4*)&lo_s[rl * 68 + 4 * cg] = make_float4(lov[0], lov[1], lov[2], lov[3]);
            *(float4*)&hi_s[rl * 68 + 4 * cg] = make_float4(hiv[0], hiv[1], hiv[2], hiv[3]);
        }
        __syncthreads();

        // ---- stage B: column filter + q2c. thread = (row-pair qi, col4 cg) ----
        {
            const int qi = t >> 4, cg = t & 15;
            float4 Lv[8];
            float llv[2][4], lhv[2][4], hlv[2][4], hhv[2][4];

#pragma unroll
            for (int j = 0; j < 8; ++j)
                Lv[j] = *(const float4*)&lo_s[(2 * qi + j) * 68 + 4 * cg];
            {
                const float* L = (const float*)Lv;
#pragma unroll
                for (int cc = 0; cc < 4; ++cc) {
                    float Lc[8];
#pragma unroll
                    for (int j = 0; j < 8; ++j) Lc[j] = L[4 * j + cc];
                    llv[0][cc] = f0[0]*Lc[5] + f0[1]*Lc[4] + f0[2]*Lc[3] + f0[3]*Lc[2] + f0[4]*Lc[1];
                    llv[1][cc] = f0[0]*Lc[6] + f0[1]*Lc[5] + f0[2]*Lc[4] + f0[3]*Lc[3] + f0[4]*Lc[2];
                    lhv[0][cc] = f1[0]*Lc[6] + f1[1]*Lc[5] + f1[2]*Lc[4] + f1[3]*Lc[3]
                               + f1[4]*Lc[2] + f1[5]*Lc[1] + f1[6]*Lc[0];
                    lhv[1][cc] = f1[0]*Lc[7] + f1[1]*Lc[6] + f1[2]*Lc[5] + f1[3]*Lc[4]
                               + f1[4]*Lc[3] + f1[5]*Lc[2] + f1[6]*Lc[1];
                }
            }
#pragma unroll
            for (int j = 0; j < 8; ++j)
                Lv[j] = *(const float4*)&hi_s[(2 * qi + j) * 68 + 4 * cg];
            {
                const float* L = (const float*)Lv;
#pragma unroll
                for (int cc = 0; cc < 4; ++cc) {
                    float Lc[8];
#pragma unroll
                    for (int j = 0; j < 8; ++j) Lc[j] = L[4 * j + cc];
                    hlv[0][cc] = f0[0]*Lc[5] + f0[1]*Lc[4] + f0[2]*Lc[3] + f0[3]*Lc[2] + f0[4]*Lc[1];
                    hlv[1][cc] = f0[0]*Lc[6] + f0[1]*Lc[5] + f0[2]*Lc[4] + f0[3]*Lc[3] + f0[4]*Lc[2];
                    hhv[0][cc] = f1[0]*Lc[6] + f1[1]*Lc[5] + f1[2]*Lc[4] + f1[3]*Lc[3]
                               + f1[4]*Lc[2] + f1[5]*Lc[1] + f1[6]*Lc[0];
                    hhv[1][cc] = f1[0]*Lc[7] + f1[1]*Lc[6] + f1[2]*Lc[5] + f1[3]*Lc[4]
                               + f1[4]*Lc[3] + f1[5]*Lc[2] + f1[6]*Lc[1];
                }
            }

            const int oy = r0 + 32 * h + 2 * qi, ox = c0 + 4 * cg;
            *(float4*)&lln[(size_t)oy * S1 + ox] =
                make_float4(llv[0][0], llv[0][1], llv[0][2], llv[0][3]);
            *(float4*)&lln[(size_t)(oy + 1) * S1 + ox] =
                make_float4(llv[1][0], llv[1][1], llv[1][2], llv[1][3]);

            // q2c for two quads (cols [0,1] and [2,3] of this group)
            const int i2 = (r0 >> 1) + 16 * h + qi, j2 = (c0 >> 1) + 2 * cg;
            const size_t bs = 256 * 256 * 2;
            float* __restrict__ p = yhn + ((size_t)i2 * 256 + j2) * 2;
#define ST_Z1(P, X0, X1) st_nt_f4((P), (X0[0]-X1[1])*SQH, (X0[1]+X1[0])*SQH, \
                                       (X0[2]-X1[3])*SQH, (X0[3]+X1[2])*SQH)
#define ST_Z2(P, X0, X1) st_nt_f4((P), (X0[0]+X1[1])*SQH, (X0[1]-X1[0])*SQH, \
                                       (X0[2]+X1[3])*SQH, (X0[3]-X1[2])*SQH)
            ST_Z1(p + 0 * bs, lhv[0], lhv[1]);
            ST_Z1(p + 1 * bs, hhv[0], hhv[1]);
            ST_Z1(p + 2 * bs, hlv[0], hlv[1]);
            ST_Z2(p + 3 * bs, hlv[0], hlv[1]);
            ST_Z2(p + 4 * bs, hhv[0], hhv[1]);
            ST_Z2(p + 5 * bs, lhv[0], lhv[1]);
#undef ST_Z1
#undef ST_Z2
        }
        __syncthreads();
    }
}

// ---------------------------------------------------------------------------
// Levels 2/3: decimating dual-tree 10-tap filters, fused W + H + q2c.
// 32x32 output tile.
// CHANGE vs prev: no LDS input staging (was 26.25 KB Xs). The W-filter reads
// its 20-float window directly from global (5x overlap absorbed by L1).
// LDS 48.75 -> 23.0 KB, barriers 2 -> 1, occupancy 3 -> 5 blocks/CU.
// ---------------------------------------------------------------------------
__global__ __launch_bounds__(256, 5) void k_dfilt(
    const float* __restrict__ X, const int r,
    const float* __restrict__ h0a_g, const float* __restrict__ h0b_g,
    const float* __restrict__ h1a_g, const float* __restrict__ h1b_g,
    float* __restrict__ llo, float* __restrict__ yh)
{
    __shared__ float lo_s[80 * 36];   // 11.25 KB
    __shared__ float hi_s[80 * 36];   // 11.25 KB

    const int t  = threadIdx.x;
    const int x0 = blockIdx.x * 32;
    const int y0 = blockIdx.y * 32;
    const int n  = blockIdx.z;
    const float* __restrict__ Xn = X + (size_t)n * r * r;
    const int cb = 2 * x0 - 8, rb = 2 * y0 - 8;

    float fa0[10], fb0[10], fa1[10], fb1[10];
#pragma unroll
    for (int i = 0; i < 10; ++i) {
        fa0[i] = h0a_g[i]; fb0[i] = h0b_g[i];
        fa1[i] = h1a_g[i]; fb1[i] = h1b_g[i];
    }

    const bool safe = (cb >= 0) && (cb + 95 < r);   // all windows in-bounds

    // ---- stage A: W-direction decimating filter straight from global ----
    // item (rl, cp): window = global cols cb+4cp .. cb+4cp+19,
    // row refl(rb+rl, r). 80x16 items = exactly 5 iterations of 256 threads.
    for (int l = t; l < 80 * 16; l += 256) {
        int rl = l >> 4, cp = l & 15;
        int ar = refl(rb + rl, r);
        const float* __restrict__ row = &Xn[(size_t)ar * r];
        const int gc0 = cb + 4 * cp;
        float V[20];
        if (safe || (gc0 >= 0 && gc0 + 19 < r)) {
#pragma unroll
            for (int j = 0; j < 5; ++j) {
                float4 v = *(const float4*)&row[gc0 + 4 * j];
                V[4*j+0] = v.x; V[4*j+1] = v.y; V[4*j+2] = v.z; V[4*j+3] = v.w;
            }
        } else {
#pragma unroll
            for (int k = 0; k < 20; ++k)
                V[k] = row[refl(gc0 + k, r)];
        }
        float lo_e = 0.f, lo_o = 0.f, hi_e = 0.f, hi_o = 0.f;
#pragma unroll
        for (int k = 0; k < 10; ++k) {
            float ve = V[18 - 2 * k], vo = V[19 - 2 * k];
            lo_e += fb0[k] * ve;
            lo_o += fa0[k] * vo;
            hi_e += fa1[k] * vo;
            hi_o += fb1[k] * ve;
        }
        *(float2*)&lo_s[rl * 36 + 2 * cp] = make_float2(lo_e, lo_o);
        *(float2*)&hi_s[rl * 36 + 2 * cp] = make_float2(hi_e, hi_o);
    }
    __syncthreads();

    // ---- stage B: H-direction filter + q2c, one quad per thread ----
    {
        const int qi = t >> 4, cg = t & 15;
        float2 Lv[20];
        float llq[2][2], lhq[2][2], hlq[2][2], hhq[2][2];

#pragma unroll
        for (int j = 0; j < 20; ++j)
            Lv[j] = *(const float2*)&lo_s[(4 * qi + j) * 36 + 2 * cg];
        {
            const float* L = (const float*)Lv;
#pragma unroll
            for (int cc = 0; cc < 2; ++cc) {
                float e0 = 0.f, o0 = 0.f, e1 = 0.f, o1 = 0.f;
#pragma unroll
                for (int k = 0; k < 10; ++k) {
                    float le = L[(18 - 2 * k) * 2 + cc], lo = L[(19 - 2 * k) * 2 + cc];
                    e0 += fb0[k] * le;
                    o0 += fa0[k] * lo;
                    e1 += fa1[k] * lo;
                    o1 += fb1[k] * le;
                }
                llq[0][cc] = e0; llq[1][cc] = o0;
                lhq[0][cc] = e1; lhq[1][cc] = o1;
            }
        }
#pragma unroll
        for (int j = 0; j < 20; ++j)
            Lv[j] = *(const float2*)&hi_s[(4 * qi + j) * 36 + 2 * cg];
        {
            const float* L = (const float*)Lv;
#pragma unroll
            for (int cc = 0; cc < 2; ++cc) {
                float e0 = 0.f, o0 = 0.f, e1 = 0.f, o1 = 0.f;
#pragma unroll
                for (int k = 0; k < 10; ++k) {
                    float he = L[(18 - 2 * k) * 2 + cc], ho = L[(19 - 2 * k) * 2 + cc];
                    e0 += fb0[k] * he;
                    o0 += fa0[k] * ho;
                    e1 += fa1[k] * ho;
                    o1 += fb1[k] * he;
                }
                hlq[0][cc] = e0; hlq[1][cc] = o0;
                hhq[0][cc] = e1; hhq[1][cc] = o1;
            }
        }

        const int R = r >> 1, R2 = r >> 2;
        const int oy = y0 + 2 * qi, ox = x0 + 2 * cg;
        *(float2*)&llo[((size_t)n * R + oy) * R + ox]     = make_float2(llq[0][0], llq[0][1]);
        *(float2*)&llo[((size_t)n * R + oy + 1) * R + ox] = make_float2(llq[1][0], llq[1][1]);

        const float SQH = 0.70710678118654752440f;
        const int i2 = (y0 >> 1) + qi, j2 = (x0 >> 1) + cg;
        const size_t bs = (size_t)R2 * R2 * 2;
        float* __restrict__ p = yh + (size_t)n * 6 * bs + ((size_t)i2 * R2 + j2) * 2;
        st_nt_f2(p + 0 * bs, (lhq[0][0] - lhq[1][1]) * SQH, (lhq[0][1] + lhq[1][0]) * SQH);
        st_nt_f2(p + 1 * bs, (hhq[0][0] - hhq[1][1]) * SQH, (hhq[0][1] + hhq[1][0]) * SQH);
        st_nt_f2(p + 2 * bs, (hlq[0][0] - hlq[1][1]) * SQH, (hlq[0][1] + hlq[1][0]) * SQH);
        st_nt_f2(p + 3 * bs, (hlq[0][0] + hlq[1][1]) * SQH, (hlq[0][1] - hlq[1][0]) * SQH);
        st_nt_f2(p + 4 * bs, (hhq[0][0] + hhq[1][1]) * SQH, (hhq[0][1] - hhq[1][0]) * SQH);
        st_nt_f2(p + 5 * bs, (lhq[0][0] + lhq[1][1]) * SQH, (lhq[0][1] - lhq[1][0]) * SQH);
    }
}

extern "C" void kernel_launch(void* const* d_in, const int* in_sizes, int n_in,
                              void* d_out, int out_size, void* d_ws, size_t ws_size,
                              hipStream_t stream) {
    const float* x   = (const float*)d_in[0];
    const float* h0o = (const float*)d_in[1];
    const float* h1o = (const float*)d_in[2];
    const float* h0a = (const float*)d_in[3];
    const float* h0b = (const float*)d_in[4];
    const float* h1a = (const float*)d_in[5];
    const float* h1b = (const float*)d_in[6];

    float* out = (float*)d_out;
    // output layout (flat, return order): ll3, yh0, yh1, yh2
    float* ll3 = out;                       // 64*128*128          = 1,048,576
    float* yh0 = out + 1048576;             // 64*6*256*256*2      = 50,331,648
    float* yh1 = out + 51380224;            // 64*6*128*128*2      = 12,582,912
    float* yh2 = out + 63963136;            // 64*6*64*64*2        =  3,145,728

    // workspace: ll1 (64 MB) + ll2 (16 MB)
    float* ll1 = (float*)d_ws;              // 64*512*512 floats
    float* ll2 = ll1 + 16777216;            // 64*256*256 floats

    k_level1<<<dim3(8, 8, NIMG), 256, 0, stream>>>(x, h0o, h1o, ll1, yh0);
    k_dfilt<<<dim3(8, 8, NIMG), 256, 0, stream>>>(ll1, 512, h0a, h0b, h1a, h1b, ll2, yh1);
    k_dfilt<<<dim3(4, 4, NIMG), 256, 0, stream>>>(ll2, 256, h0a, h0b, h1a, h1b, ll3, yh2);
}

// Round 3
// 376.362 us; speedup vs baseline: 1.1246x; 1.1246x over previous
//
#include <hip/hip_runtime.h>

#define S1 512
#define NIMG 64

typedef float f4v __attribute__((ext_vector_type(4)));
typedef float f2v __attribute__((ext_vector_type(2)));

__device__ __forceinline__ int refl(int a, int L) {
    a = (a < 0) ? (-a - 1) : a;
    a = (a >= L) ? (2 * L - 1 - a) : a;
    return a;
}

// Non-temporal stores for write-only wavelet bands (never re-read; keep
// ll1/ll2 resident in L2/L3 for the next level's fetch instead).
__device__ __forceinline__ void st_nt_f4(float* p, float a, float b, float c, float d) {
    f4v w = {a, b, c, d};
    __builtin_nontemporal_store(w, (f4v*)p);
}
__device__ __forceinline__ void st_nt_f2(float* p, float a, float b) {
    f2v w = {a, b};
    __builtin_nontemporal_store(w, (f2v*)p);
}

// ---------------------------------------------------------------------------
// Level 1: undecimated 5/7-tap filters, fused W-pass + H-pass + q2c.
// 64x64 output tile per block, processed as two 32-row halves to keep LDS at
// ~31.6 KB (5 blocks/CU). All LDS access vectorized (b128).
// (Identical to the verified 381.8 us version — LDS staging retained; R2
// showed direct-global stage A is a 41 us regression.)
// ---------------------------------------------------------------------------
__global__ __launch_bounds__(256) void k_level1(
    const float* __restrict__ x,
    const float* __restrict__ h0o_g, const float* __restrict__ h1o_g,
    float* __restrict__ ll1, float* __restrict__ yh0)
{
    __shared__ float xs[38 * 72];     // 10.94 KB
    __shared__ float lo_s[38 * 68];   // 10.33 KB
    __shared__ float hi_s[38 * 68];   // 10.33 KB

    const int t  = threadIdx.x;
    const int c0 = blockIdx.x * 64;
    const int r0 = blockIdx.y * 64;
    const int n  = blockIdx.z;
    const float* __restrict__ xn  = x   + (size_t)n * (S1 * S1);
    float* __restrict__ lln       = ll1 + (size_t)n * (S1 * S1);
    float* __restrict__ yhn       = yh0 + (size_t)n * (6 * 256 * 256 * 2);

    float f0[5], f1[7];
#pragma unroll
    for (int i = 0; i < 5; ++i) f0[i] = h0o_g[i];
#pragma unroll
    for (int i = 0; i < 7; ++i) f1[i] = h1o_g[i];

    const float SQH = 0.70710678118654752440f;

    for (int h = 0; h < 2; ++h) {
        const int gr0 = r0 + 32 * h - 3;

        // ---- stage 1: global -> xs (38 rows x 72 cols) ----
        // core: xs cols [4,68) <- global cols [c0, c0+64)  (always valid)
        for (int l = t; l < 38 * 16; l += 256) {
            int rl = l >> 4, cf = l & 15;
            int ar = refl(gr0 + rl, S1);
            *(float4*)&xs[rl * 72 + 4 + 4 * cf] =
                *(const float4*)&xn[(size_t)ar * S1 + c0 + 4 * cf];
        }
        // halo: xs cols [0,4) <- global [c0-4,c0); xs cols [68,72) <- [c0+64,c0+68)
        if (t < 76) {
            int rl = t >> 1, side = t & 1;
            const float* __restrict__ row = &xn[(size_t)refl(gr0 + rl, S1) * S1];
            int xc = side ? 68 : 0;
            int gc = side ? (c0 + 64) : (c0 - 4);
            if (gc >= 0 && gc + 3 < S1) {
                *(float4*)&xs[rl * 72 + xc] = *(const float4*)&row[gc];
            } else {
#pragma unroll
                for (int k = 0; k < 4; ++k)
                    xs[rl * 72 + xc + k] = row[refl(gc + k, S1)];
            }
        }
        __syncthreads();

        // ---- stage 2: row filter, 4 outputs per item ----
        // lo[c] uses xs j = c+2..c+6 ; hi[c] uses j = c+1..c+7
        for (int l = t; l < 38 * 16; l += 256) {
            int rl = l >> 4, cg = l & 15;
            const float* p = &xs[rl * 72 + 4 * cg];
            float4 va = *(const float4*)p;
            float4 vb = *(const float4*)(p + 4);
            float4 vc = *(const float4*)(p + 8);
            float V[12] = {va.x, va.y, va.z, va.w, vb.x, vb.y, vb.z, vb.w,
                           vc.x, vc.y, vc.z, vc.w};
            float lov[4], hiv[4];
#pragma unroll
            for (int cc = 0; cc < 4; ++cc) {
                lov[cc] = f0[0]*V[cc+6] + f0[1]*V[cc+5] + f0[2]*V[cc+4]
                        + f0[3]*V[cc+3] + f0[4]*V[cc+2];
                hiv[cc] = f1[0]*V[cc+7] + f1[1]*V[cc+6] + f1[2]*V[cc+5]
                        + f1[3]*V[cc+4] + f1[4]*V[cc+3] + f1[5]*V[cc+2]
                        + f1[6]*V[cc+1];
            }
            *(float4*)&lo_s[rl * 68 + 4 * cg] = make_float4(lov[0], lov[1], lov[2], lov[3]);
            *(float4*)&hi_s[rl * 68 + 4 * cg] = make_float4(hiv[0], hiv[1], hiv[2], hiv[3]);
        }
        __syncthreads();

        // ---- stage 3: column filter + q2c. thread = (row-pair qi, col4 cg) ----
        {
            const int qi = t >> 4, cg = t & 15;
            float4 Lv[8];
            float llv[2][4], lhv[2][4], hlv[2][4], hhv[2][4];

#pragma unroll
            for (int j = 0; j < 8; ++j)
                Lv[j] = *(const float4*)&lo_s[(2 * qi + j) * 68 + 4 * cg];
            {
                const float* L = (const float*)Lv;
#pragma unroll
                for (int cc = 0; cc < 4; ++cc) {
                    float Lc[8];
#pragma unroll
                    for (int j = 0; j < 8; ++j) Lc[j] = L[4 * j + cc];
                    llv[0][cc] = f0[0]*Lc[5] + f0[1]*Lc[4] + f0[2]*Lc[3] + f0[3]*Lc[2] + f0[4]*Lc[1];
                    llv[1][cc] = f0[0]*Lc[6] + f0[1]*Lc[5] + f0[2]*Lc[4] + f0[3]*Lc[3] + f0[4]*Lc[2];
                    lhv[0][cc] = f1[0]*Lc[6] + f1[1]*Lc[5] + f1[2]*Lc[4] + f1[3]*Lc[3]
                               + f1[4]*Lc[2] + f1[5]*Lc[1] + f1[6]*Lc[0];
                    lhv[1][cc] = f1[0]*Lc[7] + f1[1]*Lc[6] + f1[2]*Lc[5] + f1[3]*Lc[4]
                               + f1[4]*Lc[3] + f1[5]*Lc[2] + f1[6]*Lc[1];
                }
            }
#pragma unroll
            for (int j = 0; j < 8; ++j)
                Lv[j] = *(const float4*)&hi_s[(2 * qi + j) * 68 + 4 * cg];
            {
                const float* L = (const float*)Lv;
#pragma unroll
                for (int cc = 0; cc < 4; ++cc) {
                    float Lc[8];
#pragma unroll
                    for (int j = 0; j < 8; ++j) Lc[j] = L[4 * j + cc];
                    hlv[0][cc] = f0[0]*Lc[5] + f0[1]*Lc[4] + f0[2]*Lc[3] + f0[3]*Lc[2] + f0[4]*Lc[1];
                    hlv[1][cc] = f0[0]*Lc[6] + f0[1]*Lc[5] + f0[2]*Lc[4] + f0[3]*Lc[3] + f0[4]*Lc[2];
                    hhv[0][cc] = f1[0]*Lc[6] + f1[1]*Lc[5] + f1[2]*Lc[4] + f1[3]*Lc[3]
                               + f1[4]*Lc[2] + f1[5]*Lc[1] + f1[6]*Lc[0];
                    hhv[1][cc] = f1[0]*Lc[7] + f1[1]*Lc[6] + f1[2]*Lc[5] + f1[3]*Lc[4]
                               + f1[4]*Lc[3] + f1[5]*Lc[2] + f1[6]*Lc[1];
                }
            }

            const int oy = r0 + 32 * h + 2 * qi, ox = c0 + 4 * cg;
            *(float4*)&lln[(size_t)oy * S1 + ox] =
                make_float4(llv[0][0], llv[0][1], llv[0][2], llv[0][3]);
            *(float4*)&lln[(size_t)(oy + 1) * S1 + ox] =
                make_float4(llv[1][0], llv[1][1], llv[1][2], llv[1][3]);

            // q2c for two quads (cols [0,1] and [2,3] of this group)
            const int i2 = (r0 >> 1) + 16 * h + qi, j2 = (c0 >> 1) + 2 * cg;
            const size_t bs = 256 * 256 * 2;
            float* __restrict__ p = yhn + ((size_t)i2 * 256 + j2) * 2;
#define ST_Z1(P, X0, X1) st_nt_f4((P), (X0[0]-X1[1])*SQH, (X0[1]+X1[0])*SQH, \
                                       (X0[2]-X1[3])*SQH, (X0[3]+X1[2])*SQH)
#define ST_Z2(P, X0, X1) st_nt_f4((P), (X0[0]+X1[1])*SQH, (X0[1]-X1[0])*SQH, \
                                       (X0[2]+X1[3])*SQH, (X0[3]-X1[2])*SQH)
            ST_Z1(p + 0 * bs, lhv[0], lhv[1]);
            ST_Z1(p + 1 * bs, hhv[0], hhv[1]);
            ST_Z1(p + 2 * bs, hlv[0], hlv[1]);
            ST_Z2(p + 3 * bs, hlv[0], hlv[1]);
            ST_Z2(p + 4 * bs, hhv[0], hhv[1]);
            ST_Z2(p + 5 * bs, lhv[0], lhv[1]);
#undef ST_Z1
#undef ST_Z2
        }
        __syncthreads();
    }
}

// ---------------------------------------------------------------------------
// Levels 2/3: decimating dual-tree 10-tap filters, fused W + H + q2c.
// 32x32 output tile.
// CHANGE vs R1: the 80x84 input tile is streamed through a 16-row chunk
// buffer (5.25 KB) instead of being fully resident (26.25 KB). Stage A
// consumes each chunk into the persistent lo_s/hi_s. LDS 48.75 -> 27.75 KB,
// occupancy 3 -> 5 blocks/CU. Each chunk round is exactly 256 load items and
// 256 filter items (no imbalance). Barriers 2 -> 10, which 5 resident blocks
// hide (k1 runs 6 at the same occupancy).
// ---------------------------------------------------------------------------
__global__ __launch_bounds__(256) void k_dfilt(
    const float* __restrict__ X, const int r,
    const float* __restrict__ h0a_g, const float* __restrict__ h0b_g,
    const float* __restrict__ h1a_g, const float* __restrict__ h1b_g,
    float* __restrict__ llo, float* __restrict__ yh)
{
    __shared__ float Xc[16 * 84];     // 5.25 KB chunk of the input tile
    __shared__ float lo_s[80 * 36];   // 11.25 KB
    __shared__ float hi_s[80 * 36];   // 11.25 KB

    const int t  = threadIdx.x;
    const int x0 = blockIdx.x * 32;
    const int y0 = blockIdx.y * 32;
    const int n  = blockIdx.z;
    const float* __restrict__ Xn = X + (size_t)n * r * r;
    const int cb = 2 * x0 - 8, rb = 2 * y0 - 8;

    float fa0[10], fb0[10], fa1[10], fb1[10];
#pragma unroll
    for (int i = 0; i < 10; ++i) {
        fa0[i] = h0a_g[i]; fb0[i] = h0b_g[i];
        fa1[i] = h1a_g[i]; fb1[i] = h1b_g[i];
    }

    // ---- stages 1+2 fused, streamed over 5 chunks of 16 rows ----
    // Xc row rl <-> global row refl(rb + 16c + rl); Xc col cl <-> global col
    // cb + cl, cl in [0,80) (core [8,72) always in-bounds, halos guarded).
    for (int c = 0; c < 5; ++c) {
        const int rbase = rb + 16 * c;
        {   // core load: 16 rows x 16 float4 = exactly one item per thread
            int rl = t >> 4, cf = t & 15;
            int ar = refl(rbase + rl, r);
            *(float4*)&Xc[rl * 84 + 8 + 4 * cf] =
                *(const float4*)&Xn[(size_t)ar * r + (cb + 8) + 4 * cf];
        }
        if (t < 64) {   // halo: cols [0,8) and [72,80)
            int rl = t >> 2, q = t & 3;            // q 0,1: left; 2,3: right
            const float* __restrict__ row = &Xn[(size_t)refl(rbase + rl, r) * r];
            int xc = (q < 2) ? (4 * q) : (72 + 4 * (q - 2));
            int gc = cb + xc;
            if (gc >= 0 && gc + 3 < r) {
                *(float4*)&Xc[rl * 84 + xc] = *(const float4*)&row[gc];
            } else {
#pragma unroll
                for (int k = 0; k < 4; ++k)
                    Xc[rl * 84 + xc + k] = row[refl(gc + k, r)];
            }
        }
        __syncthreads();

        {   // W-direction decimating filter: 16 rows x 16 col-pairs
            int rl = t >> 4, cp = t & 15;
            const float* p = &Xc[rl * 84 + 4 * cp];
            float V[20];
#pragma unroll
            for (int j = 0; j < 5; ++j) {
                float4 v = *(const float4*)(p + 4 * j);
                V[4*j+0] = v.x; V[4*j+1] = v.y; V[4*j+2] = v.z; V[4*j+3] = v.w;
            }
            float lo_e = 0.f, lo_o = 0.f, hi_e = 0.f, hi_o = 0.f;
#pragma unroll
            for (int k = 0; k < 10; ++k) {
                float ve = V[18 - 2 * k], vo = V[19 - 2 * k];
                lo_e += fb0[k] * ve;
                lo_o += fa0[k] * vo;
                hi_e += fa1[k] * vo;
                hi_o += fb1[k] * ve;
            }
            const int row = 16 * c + (t >> 4);
            *(float2*)&lo_s[row * 36 + 2 * cp] = make_float2(lo_e, lo_o);
            *(float2*)&hi_s[row * 36 + 2 * cp] = make_float2(hi_e, hi_o);
        }
        __syncthreads();   // before next chunk overwrites Xc
    }

    // ---- stage 3: H-direction filter + q2c, one quad per thread ----
    {
        const int qi = t >> 4, cg = t & 15;
        float2 Lv[20];
        float llq[2][2], lhq[2][2], hlq[2][2], hhq[2][2];

#pragma unroll
        for (int j = 0; j < 20; ++j)
            Lv[j] = *(const float2*)&lo_s[(4 * qi + j) * 36 + 2 * cg];
        {
            const float* L = (const float*)Lv;
#pragma unroll
            for (int cc = 0; cc < 2; ++cc) {
                float e0 = 0.f, o0 = 0.f, e1 = 0.f, o1 = 0.f;
#pragma unroll
                for (int k = 0; k < 10; ++k) {
                    float le = L[(18 - 2 * k) * 2 + cc], lo = L[(19 - 2 * k) * 2 + cc];
                    e0 += fb0[k] * le;
                    o0 += fa0[k] * lo;
                    e1 += fa1[k] * lo;
                    o1 += fb1[k] * le;
                }
                llq[0][cc] = e0; llq[1][cc] = o0;
                lhq[0][cc] = e1; lhq[1][cc] = o1;
            }
        }
#pragma unroll
        for (int j = 0; j < 20; ++j)
            Lv[j] = *(const float2*)&hi_s[(4 * qi + j) * 36 + 2 * cg];
        {
            const float* L = (const float*)Lv;
#pragma unroll
            for (int cc = 0; cc < 2; ++cc) {
                float e0 = 0.f, o0 = 0.f, e1 = 0.f, o1 = 0.f;
#pragma unroll
                for (int k = 0; k < 10; ++k) {
                    float he = L[(18 - 2 * k) * 2 + cc], ho = L[(19 - 2 * k) * 2 + cc];
                    e0 += fb0[k] * he;
                    o0 += fa0[k] * ho;
                    e1 += fa1[k] * ho;
                    o1 += fb1[k] * he;
                }
                hlq[0][cc] = e0; hlq[1][cc] = o0;
                hhq[0][cc] = e1; hhq[1][cc] = o1;
            }
        }

        const int R = r >> 1, R2 = r >> 2;
        const int oy = y0 + 2 * qi, ox = x0 + 2 * cg;
        *(float2*)&llo[((size_t)n * R + oy) * R + ox]     = make_float2(llq[0][0], llq[0][1]);
        *(float2*)&llo[((size_t)n * R + oy + 1) * R + ox] = make_float2(llq[1][0], llq[1][1]);

        const float SQH = 0.70710678118654752440f;
        const int i2 = (y0 >> 1) + qi, j2 = (x0 >> 1) + cg;
        const size_t bs = (size_t)R2 * R2 * 2;
        float* __restrict__ p = yh + (size_t)n * 6 * bs + ((size_t)i2 * R2 + j2) * 2;
        st_nt_f2(p + 0 * bs, (lhq[0][0] - lhq[1][1]) * SQH, (lhq[0][1] + lhq[1][0]) * SQH);
        st_nt_f2(p + 1 * bs, (hhq[0][0] - hhq[1][1]) * SQH, (hhq[0][1] + hhq[1][0]) * SQH);
        st_nt_f2(p + 2 * bs, (hlq[0][0] - hlq[1][1]) * SQH, (hlq[0][1] + hlq[1][0]) * SQH);
        st_nt_f2(p + 3 * bs, (hlq[0][0] + hlq[1][1]) * SQH, (hlq[0][1] - hlq[1][0]) * SQH);
        st_nt_f2(p + 4 * bs, (hhq[0][0] + hhq[1][1]) * SQH, (hhq[0][1] - hhq[1][0]) * SQH);
        st_nt_f2(p + 5 * bs, (lhq[0][0] + lhq[1][1]) * SQH, (lhq[0][1] - lhq[1][0]) * SQH);
    }
}

extern "C" void kernel_launch(void* const* d_in, const int* in_sizes, int n_in,
                              void* d_out, int out_size, void* d_ws, size_t ws_size,
                              hipStream_t stream) {
    const float* x   = (const float*)d_in[0];
    const float* h0o = (const float*)d_in[1];
    const float* h1o = (const float*)d_in[2];
    const float* h0a = (const float*)d_in[3];
    const float* h0b = (const float*)d_in[4];
    const float* h1a = (const float*)d_in[5];
    const float* h1b = (const float*)d_in[6];

    float* out = (float*)d_out;
    // output layout (flat, return order): ll3, yh0, yh1, yh2
    float* ll3 = out;                       // 64*128*128          = 1,048,576
    float* yh0 = out + 1048576;             // 64*6*256*256*2      = 50,331,648
    float* yh1 = out + 51380224;            // 64*6*128*128*2      = 12,582,912
    float* yh2 = out + 63963136;            // 64*6*64*64*2        =  3,145,728

    // workspace: ll1 (64 MB) + ll2 (16 MB)
    float* ll1 = (float*)d_ws;              // 64*512*512 floats
    float* ll2 = ll1 + 16777216;            // 64*256*256 floats

    k_level1<<<dim3(8, 8, NIMG), 256, 0, stream>>>(x, h0o, h1o, ll1, yh0);
    k_dfilt<<<dim3(8, 8, NIMG), 256, 0, stream>>>(ll1, 512, h0a, h0b, h1a, h1b, ll2, yh1);
    k_dfilt<<<dim3(4, 4, NIMG), 256, 0, stream>>>(ll2, 256, h0a, h0b, h1a, h1b, ll3, yh2);
}

// Round 4
// 363.718 us; speedup vs baseline: 1.1637x; 1.0348x over previous
//
#include <hip/hip_runtime.h>

#define S1 512
#define NIMG 64

typedef float f4v __attribute__((ext_vector_type(4)));
typedef float f2v __attribute__((ext_vector_type(2)));

__device__ __forceinline__ int refl(int a, int L) {
    a = (a < 0) ? (-a - 1) : a;
    a = (a >= L) ? (2 * L - 1 - a) : a;
    return a;
}

// Non-temporal stores for write-only wavelet bands (never re-read; keep
// ll1/ll2 resident in L2/L3 for the next level's fetch instead).
__device__ __forceinline__ void st_nt_f4(float* p, float a, float b, float c, float d) {
    f4v w = {a, b, c, d};
    __builtin_nontemporal_store(w, (f4v*)p);
}
__device__ __forceinline__ void st_nt_f2(float* p, float a, float b) {
    f2v w = {a, b};
    __builtin_nontemporal_store(w, (f2v*)p);
}

// ---------------------------------------------------------------------------
// Level 1: undecimated 5/7-tap filters, fused W-pass + H-pass + q2c.
// 64x64 output tile per block, two 32-row halves, ~31.6 KB LDS (5 blocks/CU).
// CHANGE vs R3 (T14 async-STAGE split): half h=1's stage-1 tile is
// prefetched into REGISTERS during stage-3 of h=0 (xs is dead then), and
// ds_written to xs afterwards. Removes one full HBM-latency exposure per
// block from the critical path; barriers 6 -> 5. Math/traffic unchanged.
// ---------------------------------------------------------------------------
__global__ __launch_bounds__(256) void k_level1(
    const float* __restrict__ x,
    const float* __restrict__ h0o_g, const float* __restrict__ h1o_g,
    float* __restrict__ ll1, float* __restrict__ yh0)
{
    __shared__ float xs[38 * 72];     // 10.94 KB
    __shared__ float lo_s[38 * 68];   // 10.33 KB
    __shared__ float hi_s[38 * 68];   // 10.33 KB

    const int t  = threadIdx.x;
    const int c0 = blockIdx.x * 64;
    const int r0 = blockIdx.y * 64;
    const int n  = blockIdx.z;
    const float* __restrict__ xn  = x   + (size_t)n * (S1 * S1);
    float* __restrict__ lln       = ll1 + (size_t)n * (S1 * S1);
    float* __restrict__ yhn       = yh0 + (size_t)n * (6 * 256 * 256 * 2);

    float f0[5], f1[7];
#pragma unroll
    for (int i = 0; i < 5; ++i) f0[i] = h0o_g[i];
#pragma unroll
    for (int i = 0; i < 7; ++i) f1[i] = h1o_g[i];

    const float SQH = 0.70710678118654752440f;

    // prefetch registers for h=1's stage-1 tile (core items t, t+256, t+512; halo)
    float4 pre0, pre1, pre2, preh;

#pragma unroll
    for (int h = 0; h < 2; ++h) {
        const int gr0 = r0 + 32 * h - 3;

        if (h == 0) {
            // ---- stage 1: global -> xs (38 rows x 72 cols), direct ----
            for (int l = t; l < 38 * 16; l += 256) {
                int rl = l >> 4, cf = l & 15;
                int ar = refl(gr0 + rl, S1);
                *(float4*)&xs[rl * 72 + 4 + 4 * cf] =
                    *(const float4*)&xn[(size_t)ar * S1 + c0 + 4 * cf];
            }
            if (t < 76) {
                int rl = t >> 1, side = t & 1;
                const float* __restrict__ row = &xn[(size_t)refl(gr0 + rl, S1) * S1];
                int xc = side ? 68 : 0;
                int gc = side ? (c0 + 64) : (c0 - 4);
                if (gc >= 0 && gc + 3 < S1) {
                    *(float4*)&xs[rl * 72 + xc] = *(const float4*)&row[gc];
                } else {
#pragma unroll
                    for (int k = 0; k < 4; ++k)
                        xs[rl * 72 + xc + k] = row[refl(gc + k, S1)];
                }
            }
        } else {
            // ---- stage 1: prefetched registers -> xs ----
            {
                int rl = t >> 4, cf = t & 15;
                *(float4*)&xs[rl * 72 + 4 + 4 * cf] = pre0;
            }
            {
                int l = t + 256, rl = l >> 4, cf = l & 15;
                *(float4*)&xs[rl * 72 + 4 + 4 * cf] = pre1;
            }
            if (t < 96) {
                int l = t + 512, rl = l >> 4, cf = l & 15;
                *(float4*)&xs[rl * 72 + 4 + 4 * cf] = pre2;
            }
            if (t < 76) {
                int rl = t >> 1, side = t & 1;
                int xc = side ? 68 : 0;
                *(float4*)&xs[rl * 72 + xc] = preh;
            }
        }
        __syncthreads();

        // ---- stage 2: row filter, 4 outputs per item ----
        // lo[c] uses xs j = c+2..c+6 ; hi[c] uses j = c+1..c+7
        for (int l = t; l < 38 * 16; l += 256) {
            int rl = l >> 4, cg = l & 15;
            const float* p = &xs[rl * 72 + 4 * cg];
            float4 va = *(const float4*)p;
            float4 vb = *(const float4*)(p + 4);
            float4 vc = *(const float4*)(p + 8);
            float V[12] = {va.x, va.y, va.z, va.w, vb.x, vb.y, vb.z, vb.w,
                           vc.x, vc.y, vc.z, vc.w};
            float lov[4], hiv[4];
#pragma unroll
            for (int cc = 0; cc < 4; ++cc) {
                lov[cc] = f0[0]*V[cc+6] + f0[1]*V[cc+5] + f0[2]*V[cc+4]
                        + f0[3]*V[cc+3] + f0[4]*V[cc+2];
                hiv[cc] = f1[0]*V[cc+7] + f1[1]*V[cc+6] + f1[2]*V[cc+5]
                        + f1[3]*V[cc+4] + f1[4]*V[cc+3] + f1[5]*V[cc+2]
                        + f1[6]*V[cc+1];
            }
            *(float4*)&lo_s[rl * 68 + 4 * cg] = make_float4(lov[0], lov[1], lov[2], lov[3]);
            *(float4*)&hi_s[rl * 68 + 4 * cg] = make_float4(hiv[0], hiv[1], hiv[2], hiv[3]);
        }
        __syncthreads();

        // ---- prefetch h=1 stage-1 tile into registers (hidden under stage 3) ----
        if (h == 0) {
            const int g1 = r0 + 32 - 3;
            {
                int rl = t >> 4, cf = t & 15;
                int ar = refl(g1 + rl, S1);
                pre0 = *(const float4*)&xn[(size_t)ar * S1 + c0 + 4 * cf];
            }
            {
                int l = t + 256, rl = l >> 4, cf = l & 15;
                int ar = refl(g1 + rl, S1);
                pre1 = *(const float4*)&xn[(size_t)ar * S1 + c0 + 4 * cf];
            }
            if (t < 96) {
                int l = t + 512, rl = l >> 4, cf = l & 15;
                int ar = refl(g1 + rl, S1);
                pre2 = *(const float4*)&xn[(size_t)ar * S1 + c0 + 4 * cf];
            }
            if (t < 76) {
                int rl = t >> 1, side = t & 1;
                const float* __restrict__ row = &xn[(size_t)refl(g1 + rl, S1) * S1];
                int gc = side ? (c0 + 64) : (c0 - 4);
                if (gc >= 0 && gc + 3 < S1) {
                    preh = *(const float4*)&row[gc];
                } else {
                    float tmp[4];
#pragma unroll
                    for (int k = 0; k < 4; ++k)
                        tmp[k] = row[refl(gc + k, S1)];
                    preh = make_float4(tmp[0], tmp[1], tmp[2], tmp[3]);
                }
            }
        }

        // ---- stage 3: column filter + q2c. thread = (row-pair qi, col4 cg) ----
        {
            const int qi = t >> 4, cg = t & 15;
            float4 Lv[8];
            float llv[2][4], lhv[2][4], hlv[2][4], hhv[2][4];

#pragma unroll
            for (int j = 0; j < 8; ++j)
                Lv[j] = *(const float4*)&lo_s[(2 * qi + j) * 68 + 4 * cg];
            {
                const float* L = (const float*)Lv;
#pragma unroll
                for (int cc = 0; cc < 4; ++cc) {
                    float Lc[8];
#pragma unroll
                    for (int j = 0; j < 8; ++j) Lc[j] = L[4 * j + cc];
                    llv[0][cc] = f0[0]*Lc[5] + f0[1]*Lc[4] + f0[2]*Lc[3] + f0[3]*Lc[2] + f0[4]*Lc[1];
                    llv[1][cc] = f0[0]*Lc[6] + f0[1]*Lc[5] + f0[2]*Lc[4] + f0[3]*Lc[3] + f0[4]*Lc[2];
                    lhv[0][cc] = f1[0]*Lc[6] + f1[1]*Lc[5] + f1[2]*Lc[4] + f1[3]*Lc[3]
                               + f1[4]*Lc[2] + f1[5]*Lc[1] + f1[6]*Lc[0];
                    lhv[1][cc] = f1[0]*Lc[7] + f1[1]*Lc[6] + f1[2]*Lc[5] + f1[3]*Lc[4]
                               + f1[4]*Lc[3] + f1[5]*Lc[2] + f1[6]*Lc[1];
                }
            }
#pragma unroll
            for (int j = 0; j < 8; ++j)
                Lv[j] = *(const float4*)&hi_s[(2 * qi + j) * 68 + 4 * cg];
            {
                const float* L = (const float*)Lv;
#pragma unroll
                for (int cc = 0; cc < 4; ++cc) {
                    float Lc[8];
#pragma unroll
                    for (int j = 0; j < 8; ++j) Lc[j] = L[4 * j + cc];
                    hlv[0][cc] = f0[0]*Lc[5] + f0[1]*Lc[4] + f0[2]*Lc[3] + f0[3]*Lc[2] + f0[4]*Lc[1];
                    hlv[1][cc] = f0[0]*Lc[6] + f0[1]*Lc[5] + f0[2]*Lc[4] + f0[3]*Lc[3] + f0[4]*Lc[2];
                    hhv[0][cc] = f1[0]*Lc[6] + f1[1]*Lc[5] + f1[2]*Lc[4] + f1[3]*Lc[3]
                               + f1[4]*Lc[2] + f1[5]*Lc[1] + f1[6]*Lc[0];
                    hhv[1][cc] = f1[0]*Lc[7] + f1[1]*Lc[6] + f1[2]*Lc[5] + f1[3]*Lc[4]
                               + f1[4]*Lc[3] + f1[5]*Lc[2] + f1[6]*Lc[1];
                }
            }

            const int oy = r0 + 32 * h + 2 * qi, ox = c0 + 4 * cg;
            *(float4*)&lln[(size_t)oy * S1 + ox] =
                make_float4(llv[0][0], llv[0][1], llv[0][2], llv[0][3]);
            *(float4*)&lln[(size_t)(oy + 1) * S1 + ox] =
                make_float4(llv[1][0], llv[1][1], llv[1][2], llv[1][3]);

            // q2c for two quads (cols [0,1] and [2,3] of this group)
            const int i2 = (r0 >> 1) + 16 * h + qi, j2 = (c0 >> 1) + 2 * cg;
            const size_t bs = 256 * 256 * 2;
            float* __restrict__ p = yhn + ((size_t)i2 * 256 + j2) * 2;
#define ST_Z1(P, X0, X1) st_nt_f4((P), (X0[0]-X1[1])*SQH, (X0[1]+X1[0])*SQH, \
                                       (X0[2]-X1[3])*SQH, (X0[3]+X1[2])*SQH)
#define ST_Z2(P, X0, X1) st_nt_f4((P), (X0[0]+X1[1])*SQH, (X0[1]-X1[0])*SQH, \
                                       (X0[2]+X1[3])*SQH, (X0[3]-X1[2])*SQH)
            ST_Z1(p + 0 * bs, lhv[0], lhv[1]);
            ST_Z1(p + 1 * bs, hhv[0], hhv[1]);
            ST_Z1(p + 2 * bs, hlv[0], hlv[1]);
            ST_Z2(p + 3 * bs, hlv[0], hlv[1]);
            ST_Z2(p + 4 * bs, hhv[0], hhv[1]);
            ST_Z2(p + 5 * bs, lhv[0], lhv[1]);
#undef ST_Z1
#undef ST_Z2
        }
        if (h == 0) __syncthreads();   // before stage 2 of h=1 overwrites lo_s/hi_s
    }
}

// ---------------------------------------------------------------------------
// Levels 2/3: decimating dual-tree 10-tap filters, fused W + H + q2c.
// 32x32 output tile, input streamed in 5 chunks of 16 rows (27.75 KB LDS,
// 5 blocks/CU).
// CHANGE vs R3 (T14): each chunk is reg-staged and DOUBLE-BUFFERED in
// registers — chunk c+1's global loads are issued right after the barrier,
// while the W-filter of chunk c runs, hiding the HBM latency of 4 of the 5
// chunk loads under compute. LDS/barrier count unchanged.
// ---------------------------------------------------------------------------
__global__ __launch_bounds__(256) void k_dfilt(
    const float* __restrict__ X, const int r,
    const float* __restrict__ h0a_g, const float* __restrict__ h0b_g,
    const float* __restrict__ h1a_g, const float* __restrict__ h1b_g,
    float* __restrict__ llo, float* __restrict__ yh)
{
    __shared__ float Xc[16 * 84];     // 5.25 KB chunk of the input tile
    __shared__ float lo_s[80 * 36];   // 11.25 KB
    __shared__ float hi_s[80 * 36];   // 11.25 KB

    const int t  = threadIdx.x;
    const int x0 = blockIdx.x * 32;
    const int y0 = blockIdx.y * 32;
    const int n  = blockIdx.z;
    const float* __restrict__ Xn = X + (size_t)n * r * r;
    const int cb = 2 * x0 - 8, rb = 2 * y0 - 8;

    float fa0[10], fb0[10], fa1[10], fb1[10];
#pragma unroll
    for (int i = 0; i < 10; ++i) {
        fa0[i] = h0a_g[i]; fb0[i] = h0b_g[i];
        fa1[i] = h1a_g[i]; fb1[i] = h1b_g[i];
    }

    // chunk staging registers: core (1 float4/thread) + halo (t<64)
    float4 creg, hreg;

    auto load_chunk = [&](int c) {
        const int rbase = rb + 16 * c;
        {
            int rl = t >> 4, cf = t & 15;
            int ar = refl(rbase + rl, r);
            creg = *(const float4*)&Xn[(size_t)ar * r + (cb + 8) + 4 * cf];
        }
        if (t < 64) {
            int rl = t >> 2, q = t & 3;            // q 0,1: left; 2,3: right
            const float* __restrict__ row = &Xn[(size_t)refl(rbase + rl, r) * r];
            int xc = (q < 2) ? (4 * q) : (72 + 4 * (q - 2));
            int gc = cb + xc;
            if (gc >= 0 && gc + 3 < r) {
                hreg = *(const float4*)&row[gc];
            } else {
                float tmp[4];
#pragma unroll
                for (int k = 0; k < 4; ++k)
                    tmp[k] = row[refl(gc + k, r)];
                hreg = make_float4(tmp[0], tmp[1], tmp[2], tmp[3]);
            }
        }
    };

    load_chunk(0);

    // ---- stages 1+2 fused, streamed over 5 chunks of 16 rows ----
    for (int c = 0; c < 5; ++c) {
        {   // regs -> Xc
            int rl = t >> 4, cf = t & 15;
            *(float4*)&Xc[rl * 84 + 8 + 4 * cf] = creg;
        }
        if (t < 64) {
            int rl = t >> 2, q = t & 3;
            int xc = (q < 2) ? (4 * q) : (72 + 4 * (q - 2));
            *(float4*)&Xc[rl * 84 + xc] = hreg;
        }
        __syncthreads();

        if (c < 4) load_chunk(c + 1);   // in flight under the filter below

        {   // W-direction decimating filter: 16 rows x 16 col-pairs
            int rl = t >> 4, cp = t & 15;
            const float* p = &Xc[rl * 84 + 4 * cp];
            float V[20];
#pragma unroll
            for (int j = 0; j < 5; ++j) {
                float4 v = *(const float4*)(p + 4 * j);
                V[4*j+0] = v.x; V[4*j+1] = v.y; V[4*j+2] = v.z; V[4*j+3] = v.w;
            }
            float lo_e = 0.f, lo_o = 0.f, hi_e = 0.f, hi_o = 0.f;
#pragma unroll
            for (int k = 0; k < 10; ++k) {
                float ve = V[18 - 2 * k], vo = V[19 - 2 * k];
                lo_e += fb0[k] * ve;
                lo_o += fa0[k] * vo;
                hi_e += fa1[k] * vo;
                hi_o += fb1[k] * ve;
            }
            const int row = 16 * c + rl;
            *(float2*)&lo_s[row * 36 + 2 * cp] = make_float2(lo_e, lo_o);
            *(float2*)&hi_s[row * 36 + 2 * cp] = make_float2(hi_e, hi_o);
        }
        __syncthreads();   // before next chunk overwrites Xc
    }

    // ---- stage 3: H-direction filter + q2c, one quad per thread ----
    {
        const int qi = t >> 4, cg = t & 15;
        float2 Lv[20];
        float llq[2][2], lhq[2][2], hlq[2][2], hhq[2][2];

#pragma unroll
        for (int j = 0; j < 20; ++j)
            Lv[j] = *(const float2*)&lo_s[(4 * qi + j) * 36 + 2 * cg];
        {
            const float* L = (const float*)Lv;
#pragma unroll
            for (int cc = 0; cc < 2; ++cc) {
                float e0 = 0.f, o0 = 0.f, e1 = 0.f, o1 = 0.f;
#pragma unroll
                for (int k = 0; k < 10; ++k) {
                    float le = L[(18 - 2 * k) * 2 + cc], lo = L[(19 - 2 * k) * 2 + cc];
                    e0 += fb0[k] * le;
                    o0 += fa0[k] * lo;
                    e1 += fa1[k] * lo;
                    o1 += fb1[k] * le;
                }
                llq[0][cc] = e0; llq[1][cc] = o0;
                lhq[0][cc] = e1; lhq[1][cc] = o1;
            }
        }
#pragma unroll
        for (int j = 0; j < 20; ++j)
            Lv[j] = *(const float2*)&hi_s[(4 * qi + j) * 36 + 2 * cg];
        {
            const float* L = (const float*)Lv;
#pragma unroll
            for (int cc = 0; cc < 2; ++cc) {
                float e0 = 0.f, o0 = 0.f, e1 = 0.f, o1 = 0.f;
#pragma unroll
                for (int k = 0; k < 10; ++k) {
                    float he = L[(18 - 2 * k) * 2 + cc], ho = L[(19 - 2 * k) * 2 + cc];
                    e0 += fb0[k] * he;
                    o0 += fa0[k] * ho;
                    e1 += fa1[k] * ho;
                    o1 += fb1[k] * he;
                }
                hlq[0][cc] = e0; hlq[1][cc] = o0;
                hhq[0][cc] = e1; hhq[1][cc] = o1;
            }
        }

        const int R = r >> 1, R2 = r >> 2;
        const int oy = y0 + 2 * qi, ox = x0 + 2 * cg;
        *(float2*)&llo[((size_t)n * R + oy) * R + ox]     = make_float2(llq[0][0], llq[0][1]);
        *(float2*)&llo[((size_t)n * R + oy + 1) * R + ox] = make_float2(llq[1][0], llq[1][1]);

        const float SQH = 0.70710678118654752440f;
        const int i2 = (y0 >> 1) + qi, j2 = (x0 >> 1) + cg;
        const size_t bs = (size_t)R2 * R2 * 2;
        float* __restrict__ p = yh + (size_t)n * 6 * bs + ((size_t)i2 * R2 + j2) * 2;
        st_nt_f2(p + 0 * bs, (lhq[0][0] - lhq[1][1]) * SQH, (lhq[0][1] + lhq[1][0]) * SQH);
        st_nt_f2(p + 1 * bs, (hhq[0][0] - hhq[1][1]) * SQH, (hhq[0][1] + hhq[1][0]) * SQH);
        st_nt_f2(p + 2 * bs, (hlq[0][0] - hlq[1][1]) * SQH, (hlq[0][1] + hlq[1][0]) * SQH);
        st_nt_f2(p + 3 * bs, (hlq[0][0] + hlq[1][1]) * SQH, (hlq[0][1] - hlq[1][0]) * SQH);
        st_nt_f2(p + 4 * bs, (hhq[0][0] + hhq[1][1]) * SQH, (hhq[0][1] - hhq[1][0]) * SQH);
        st_nt_f2(p + 5 * bs, (lhq[0][0] + lhq[1][1]) * SQH, (lhq[0][1] - lhq[1][0]) * SQH);
    }
}

extern "C" void kernel_launch(void* const* d_in, const int* in_sizes, int n_in,
                              void* d_out, int out_size, void* d_ws, size_t ws_size,
                              hipStream_t stream) {
    const float* x   = (const float*)d_in[0];
    const float* h0o = (const float*)d_in[1];
    const float* h1o = (const float*)d_in[2];
    const float* h0a = (const float*)d_in[3];
    const float* h0b = (const float*)d_in[4];
    const float* h1a = (const float*)d_in[5];
    const float* h1b = (const float*)d_in[6];

    float* out = (float*)d_out;
    // output layout (flat, return order): ll3, yh0, yh1, yh2
    float* ll3 = out;                       // 64*128*128          = 1,048,576
    float* yh0 = out + 1048576;             // 64*6*256*256*2      = 50,331,648
    float* yh1 = out + 51380224;            // 64*6*128*128*2      = 12,582,912
    float* yh2 = out + 63963136;            // 64*6*64*64*2        =  3,145,728

    // workspace: ll1 (64 MB) + ll2 (16 MB)
    float* ll1 = (float*)d_ws;              // 64*512*512 floats
    float* ll2 = ll1 + 16777216;            // 64*256*256 floats

    k_level1<<<dim3(8, 8, NIMG), 256, 0, stream>>>(x, h0o, h1o, ll1, yh0);
    k_dfilt<<<dim3(8, 8, NIMG), 256, 0, stream>>>(ll1, 512, h0a, h0b, h1a, h1b, ll2, yh1);
    k_dfilt<<<dim3(4, 4, NIMG), 256, 0, stream>>>(ll2, 256, h0a, h0b, h1a, h1b, ll3, yh2);
}